// Round 3
// baseline (351.973 us; speedup 1.0000x reference)
//
#include <hip/hip_runtime.h>

// RNN_arch_2: 16-step RNN, B=16384, D_IN=64, D_H=256, D_MID=64, D_OUT=4.
// R3: occupancy was reg-capped (192 VGPR of persistent weights/wave at
// 64-col strips -> 2 waves/SIMD). Narrow to 32-col strips (wcat 80 VGPR),
// 8 waves x 32 rows per block, grid 512 -> 16 waves/CU (50% occ).
// Plus: f16 weight prepass into d_ws (half bytes, b128 frag loads),
// h double-buffer (2 barriers/step instead of 3), h-tiles-first MFMA order
// + 1-step x prefetch to hide HBM latency, mid on waves 0-3 / fc on 4-5.

typedef _Float16 half8 __attribute__((ext_vector_type(8)));
typedef float floatx4 __attribute__((ext_vector_type(4)));

#define T_STEPS  16
#define BATCH    16384
#define BLK_ROWS 32
#define HS       264   // h_lds row stride (f16)
#define MS       72    // mid_lds row stride (f16)

// d_ws layout (f16 elements): Wi[256x64], Wh[256x256], Wo[64x256], Wf[4x64]
#define WS_WI 0
#define WS_WH 16384
#define WS_WO 81920
#define WS_WF 98304
#define WS_TOT 98560

__global__ void prep_kernel(const float* __restrict__ Wi, const float* __restrict__ Wh,
                            const float* __restrict__ Wo, const float* __restrict__ Wf,
                            _Float16* __restrict__ ws) {
    int i = blockIdx.x * 256 + threadIdx.x;
    if (i >= WS_TOT) return;
    float v;
    if (i < WS_WH)      v = Wi[i];
    else if (i < WS_WO) v = Wh[i - WS_WH];
    else if (i < WS_WF) v = Wo[i - WS_WO];
    else                v = Wf[i - WS_WF];
    ws[i] = (_Float16)v;
}

__device__ inline float fast_tanh(float x) {
    float t = __builtin_amdgcn_exp2f(x * 2.8853900817779268f);
    return 1.0f - 2.0f * __builtin_amdgcn_rcpf(t + 1.0f);
}

__device__ inline half8 cvt8pair(float4 a, float4 b) {
    half8 h;
    h[0] = (_Float16)a.x; h[1] = (_Float16)a.y; h[2] = (_Float16)a.z; h[3] = (_Float16)a.w;
    h[4] = (_Float16)b.x; h[5] = (_Float16)b.y; h[6] = (_Float16)b.z; h[7] = (_Float16)b.w;
    return h;
}

__global__ __launch_bounds__(512, 4) void rnn_kernel(
    const float* __restrict__ x,    const float* __restrict__ hc1,
    const _Float16* __restrict__ wf16,
    const float* __restrict__ bi,   const float* __restrict__ bh,
    const float* __restrict__ bo,   const float* __restrict__ bfc,
    float* __restrict__ out)
{
    __shared__ _Float16 h_lds[2][BLK_ROWS * HS];   // ping-pong h (f16)
    __shared__ _Float16 mid_lds[BLK_ROWS * MS];
    __shared__ _Float16 wfc_lds[256];

    const int tid  = threadIdx.x;
    const int w    = tid >> 6;         // wave 0..7
    const int lane = tid & 63;
    const int l16  = lane & 15;
    const int quad = lane >> 4;
    const int b0   = blockIdx.x * BLK_ROWS;
    const int cb   = w * 32;           // pre-GEMM n-strip base col

    if (tid < 256) wfc_lds[tid] = wf16[WS_WF + tid];

    // biases in registers
    float bpre[2];
    #pragma unroll
    for (int nt = 0; nt < 2; ++nt) {
        int c = cb + nt * 16 + l16;
        bpre[nt] = bi[c] + bh[c];
    }
    float bo_r  = (w < 4) ? bo[w * 16 + l16] : 0.0f;
    float bfc_r = (tid >= 256 && tid < 384) ? bfc[(tid - 256) & 3] : 0.0f;

    // persistent weight fragments (f16 from ws, one b128 load each)
    // B layout: n = lane&15, k = quad*8 + j
    half8 wcat[10][2];
    #pragma unroll
    for (int ks = 0; ks < 10; ++ks) {
        #pragma unroll
        for (int nt = 0; nt < 2; ++nt) {
            int j = cb + nt * 16 + l16;
            wcat[ks][nt] = (ks < 2)
                ? *(const half8*)(wf16 + WS_WI + (size_t)j * 64  + ks * 32 + quad * 8)
                : *(const half8*)(wf16 + WS_WH + (size_t)j * 256 + (ks - 2) * 32 + quad * 8);
        }
    }
    half8 wof[8];
    if (w < 4) {
        #pragma unroll
        for (int ks = 0; ks < 8; ++ks)
            wof[ks] = *(const half8*)(wf16 + WS_WO + (size_t)(w * 16 + l16) * 256 + ks * 32 + quad * 8);
    }

    // stage hc1 -> h_lds[0]: 32 rows, 16 threads/row x 16 cols
    {
        int r = tid >> 4, c0 = (tid & 15) * 16;
        const float4* src = (const float4*)&hc1[(size_t)(b0 + r) * 256 + c0];
        float4 v0 = src[0], v1 = src[1], v2 = src[2], v3 = src[3];
        *(half8*)&h_lds[0][r * HS + c0]     = cvt8pair(v0, v1);
        *(half8*)&h_lds[0][r * HS + c0 + 8] = cvt8pair(v2, v3);
    }

    // x(0) raw prefetch (fp32, converted at consume time)
    float4 xraw[2][4];
    #pragma unroll
    for (int mt = 0; mt < 2; ++mt) {
        const float* base = x + (size_t)(b0 + mt * 16 + l16) * 64 + quad * 8;
        xraw[mt][0] = ((const float4*)base)[0];
        xraw[mt][1] = ((const float4*)base)[1];
        xraw[mt][2] = ((const float4*)(base + 32))[0];
        xraw[mt][3] = ((const float4*)(base + 32))[1];
    }

    __syncthreads();

    for (int t = 0; t < T_STEPS; ++t) {
        const int cur = t & 1, nxt = cur ^ 1;

        // convert this step's x; prefetch next step's x
        half8 afx[2][2];
        #pragma unroll
        for (int mt = 0; mt < 2; ++mt) {
            afx[mt][0] = cvt8pair(xraw[mt][0], xraw[mt][1]);
            afx[mt][1] = cvt8pair(xraw[mt][2], xraw[mt][3]);
        }
        if (t + 1 < T_STEPS) {
            #pragma unroll
            for (int mt = 0; mt < 2; ++mt) {
                const float* base = x + ((size_t)(t + 1) * BATCH + b0 + mt * 16 + l16) * 64 + quad * 8;
                xraw[mt][0] = ((const float4*)base)[0];
                xraw[mt][1] = ((const float4*)base)[1];
                xraw[mt][2] = ((const float4*)(base + 32))[0];
                xraw[mt][3] = ((const float4*)(base + 32))[1];
            }
        }

        // ---- pre = [x|h] @ [Wi;Wh]^T, K=320; h-tiles first, x-tiles last ----
        floatx4 acc[2][2];
        #pragma unroll
        for (int mt = 0; mt < 2; ++mt)
            #pragma unroll
            for (int nt = 0; nt < 2; ++nt)
                acc[mt][nt] = (floatx4){0.f, 0.f, 0.f, 0.f};

        #pragma unroll
        for (int ks = 2; ks < 10; ++ks) {
            half8 af[2];
            #pragma unroll
            for (int mt = 0; mt < 2; ++mt)
                af[mt] = *(const half8*)&h_lds[cur][(mt * 16 + l16) * HS + (ks - 2) * 32 + quad * 8];
            #pragma unroll
            for (int mt = 0; mt < 2; ++mt)
                #pragma unroll
                for (int nt = 0; nt < 2; ++nt)
                    acc[mt][nt] = __builtin_amdgcn_mfma_f32_16x16x32_f16(
                        af[mt], wcat[ks][nt], acc[mt][nt], 0, 0, 0);
        }
        #pragma unroll
        for (int ks = 0; ks < 2; ++ks)
            #pragma unroll
            for (int mt = 0; mt < 2; ++mt)
                #pragma unroll
                for (int nt = 0; nt < 2; ++nt)
                    acc[mt][nt] = __builtin_amdgcn_mfma_f32_16x16x32_f16(
                        afx[mt][ks], wcat[ks][nt], acc[mt][nt], 0, 0, 0);

        // epilogue: h_new = tanh(pre + bias) -> other h buffer
        #pragma unroll
        for (int nt = 0; nt < 2; ++nt) {
            int col = cb + nt * 16 + l16;
            #pragma unroll
            for (int mt = 0; mt < 2; ++mt)
                #pragma unroll
                for (int r = 0; r < 4; ++r) {
                    int row = mt * 16 + quad * 4 + r;
                    h_lds[nxt][row * HS + col] = (_Float16)fast_tanh(acc[mt][nt][r] + bpre[nt]);
                }
        }

        __syncthreads();   // h_new visible (write was to other buffer: no WAR barrier needed)

        // ---- mid = tanh(h_new @ Wo^T + bo): waves 0-3, 16 cols each ----
        if (w < 4) {
            floatx4 acc2[2];
            #pragma unroll
            for (int mt = 0; mt < 2; ++mt) acc2[mt] = (floatx4){0.f, 0.f, 0.f, 0.f};
            #pragma unroll
            for (int ks = 0; ks < 8; ++ks) {
                #pragma unroll
                for (int mt = 0; mt < 2; ++mt) {
                    half8 af = *(const half8*)&h_lds[nxt][(mt * 16 + l16) * HS + ks * 32 + quad * 8];
                    acc2[mt] = __builtin_amdgcn_mfma_f32_16x16x32_f16(af, wof[ks], acc2[mt], 0, 0, 0);
                }
            }
            int col = w * 16 + l16;
            #pragma unroll
            for (int mt = 0; mt < 2; ++mt)
                #pragma unroll
                for (int r = 0; r < 4; ++r) {
                    int row = mt * 16 + quad * 4 + r;
                    mid_lds[row * MS + col] = (_Float16)fast_tanh(acc2[mt][r] + bo_r);
                }
        }

        __syncthreads();   // mid visible

        // ---- out = mid @ Wfc^T + bfc: waves 4-5 (idle during mid) ----
        if (tid >= 256 && tid < 384) {
            int idx = tid - 256, row = idx >> 2, oc = idx & 3;
            float s = bfc_r;
            #pragma unroll
            for (int k8 = 0; k8 < 64; k8 += 8) {
                half8 mv = *(const half8*)&mid_lds[row * MS + k8];
                half8 wv = *(const half8*)&wfc_lds[oc * 64 + k8];
                #pragma unroll
                for (int j = 0; j < 8; ++j)
                    s += (float)mv[j] * (float)wv[j];
            }
            out[((size_t)t * BATCH + b0 + row) * 4 + oc] = s;
        }
        // no trailing barrier: next h write goes behind barrier A, mid write behind it too
    }

    // ---- h_final (fp32) at offset T*B*4; h_16 lives in h_lds[0] ----
    {
        int r = tid >> 4, c0 = (tid & 15) * 16;
        float4* dst = (float4*)&out[(size_t)T_STEPS * BATCH * 4 + (size_t)(b0 + r) * 256 + c0];
        half8 p0 = *(const half8*)&h_lds[0][r * HS + c0];
        half8 p1 = *(const half8*)&h_lds[0][r * HS + c0 + 8];
        float4 v;
        v.x = (float)p0[0]; v.y = (float)p0[1]; v.z = (float)p0[2]; v.w = (float)p0[3]; dst[0] = v;
        v.x = (float)p0[4]; v.y = (float)p0[5]; v.z = (float)p0[6]; v.w = (float)p0[7]; dst[1] = v;
        v.x = (float)p1[0]; v.y = (float)p1[1]; v.z = (float)p1[2]; v.w = (float)p1[3]; dst[2] = v;
        v.x = (float)p1[4]; v.y = (float)p1[5]; v.z = (float)p1[6]; v.w = (float)p1[7]; dst[3] = v;
    }
}

extern "C" void kernel_launch(void* const* d_in, const int* in_sizes, int n_in,
                              void* d_out, int out_size, void* d_ws, size_t ws_size,
                              hipStream_t stream) {
    const float* x   = (const float*)d_in[0];
    const float* hc1 = (const float*)d_in[1];
    const float* Wi  = (const float*)d_in[2];
    const float* bi  = (const float*)d_in[3];
    const float* Wh  = (const float*)d_in[4];
    const float* bh  = (const float*)d_in[5];
    const float* Wo  = (const float*)d_in[6];
    const float* bo  = (const float*)d_in[7];
    const float* Wf  = (const float*)d_in[8];
    const float* bf  = (const float*)d_in[9];
    _Float16* ws = (_Float16*)d_ws;

    prep_kernel<<<(WS_TOT + 255) / 256, 256, 0, stream>>>(Wi, Wh, Wo, Wf, ws);
    rnn_kernel<<<BATCH / BLK_ROWS, 512, 0, stream>>>(
        x, hc1, ws, bi, bh, bo, bf, (float*)d_out);
}

// Round 4
// 227.867 us; speedup vs baseline: 1.5446x; 1.5446x over previous
//
#include <hip/hip_runtime.h>

// RNN_arch_2: 16-step RNN, B=16384, D_IN=64, D_H=256, D_MID=64, D_OUT=4.
// R4: R3 died from spill: __launch_bounds__ 2nd arg is min BLOCKS/CU (CUDA
// semantics), so (512,4) -> 32 waves/CU -> 64-VGPR budget vs ~200 needed ->
// 555 MB scratch FETCH. Now (512,2): 2 blocks/CU, 128-VGPR cap, source
// trimmed to ~115 regs (per-mt acc processing, x staged f16 via LDS, wof
// reloaded from L2 per step in 2 half-batches). Single barrier per step via
// cross-barrier pipelining: region r = preGEMM(r) + mid(r-1) + fc(r-2) +
// xstage(r+1); h/x/mid all parity double-buffered.

typedef _Float16 half8 __attribute__((ext_vector_type(8)));
typedef _Float16 half4 __attribute__((ext_vector_type(4)));
typedef float floatx4 __attribute__((ext_vector_type(4)));

#define T_STEPS  16
#define BATCH    16384
#define BLK_ROWS 32
#define HS       264   // h_lds row stride (f16): 528 B -> 2-way bank alias (free)
#define XS       72    // x_lds row stride (f16): 144 B -> 2-way
#define MS       72    // mid_lds row stride

// ws layout (f16): Wi[256x64], Wh[256x256], Wo[64x256], Wf[4x64]
#define WS_WI 0
#define WS_WH 16384
#define WS_WO 81920
#define WS_WF 98304
#define WS_TOT 98560

__global__ void prep_kernel(const float* __restrict__ Wi, const float* __restrict__ Wh,
                            const float* __restrict__ Wo, const float* __restrict__ Wf,
                            _Float16* __restrict__ ws) {
    int i = blockIdx.x * 256 + threadIdx.x;
    if (i >= WS_TOT) return;
    float v;
    if (i < WS_WH)      v = Wi[i];
    else if (i < WS_WO) v = Wh[i - WS_WH];
    else if (i < WS_WF) v = Wo[i - WS_WO];
    else                v = Wf[i - WS_WF];
    ws[i] = (_Float16)v;
}

__device__ inline float fast_tanh(float x) {
    float t = __builtin_amdgcn_exp2f(x * 2.8853900817779268f);
    return 1.0f - 2.0f * __builtin_amdgcn_rcpf(t + 1.0f);
}

__device__ inline half8 cvt8pair(float4 a, float4 b) {
    half8 h;
    h[0] = (_Float16)a.x; h[1] = (_Float16)a.y; h[2] = (_Float16)a.z; h[3] = (_Float16)a.w;
    h[4] = (_Float16)b.x; h[5] = (_Float16)b.y; h[6] = (_Float16)b.z; h[7] = (_Float16)b.w;
    return h;
}

#define MFMA(a, b, c) __builtin_amdgcn_mfma_f32_16x16x32_f16((a), (b), (c), 0, 0, 0)

__global__ __launch_bounds__(512, 2) void rnn_kernel(
    const float* __restrict__ x,    const float* __restrict__ hc1,
    const _Float16* __restrict__ wf16,
    const float* __restrict__ bi,   const float* __restrict__ bh,
    const float* __restrict__ bo,   const float* __restrict__ bfc,
    float* __restrict__ out)
{
    __shared__ _Float16 h_lds[2][BLK_ROWS * HS];   // h state, parity dbuf
    __shared__ _Float16 xf[2][BLK_ROWS * XS];      // x_t (f16), parity dbuf
    __shared__ _Float16 midb[2][BLK_ROWS * MS];    // tanh(h2o), parity dbuf
    __shared__ _Float16 wfc_lds[256];

    const int tid  = threadIdx.x;
    const int w    = tid >> 6;        // wave 0..7 -> 32-col strip of pre
    const int lane = tid & 63;
    const int l16  = lane & 15;
    const int quad = lane >> 4;
    const int b0   = blockIdx.x * BLK_ROWS;

    if (tid < 256) wfc_lds[tid] = wf16[WS_WF + tid];

    // biases (registers)
    float bpre[2];
    #pragma unroll
    for (int nt = 0; nt < 2; ++nt) {
        int c = w * 32 + nt * 16 + l16;
        bpre[nt] = bi[c] + bh[c];
    }
    const int midc  = (w >> 1) * 16 + l16;   // mid tile out-col (tile nt = w>>1)
    const int midmt = w & 1;                 // mid tile row group
    float bo_r  = bo[midc];
    float bfc_r = (tid < 128) ? bfc[tid & 3] : 0.0f;

    // persistent pre-GEMM weight fragments: B-frag n = l16, k = quad*8+j
    half8 wcat[10][2];
    #pragma unroll
    for (int ks = 0; ks < 10; ++ks) {
        #pragma unroll
        for (int nt = 0; nt < 2; ++nt) {
            int j = w * 32 + nt * 16 + l16;
            wcat[ks][nt] = (ks < 2)
                ? *(const half8*)(wf16 + WS_WI + (size_t)j * 64  + ks * 32 + quad * 8)
                : *(const half8*)(wf16 + WS_WH + (size_t)j * 256 + (ks - 2) * 32 + quad * 8);
        }
    }

    // stage hc1 -> h_lds[0]: 512 threads x 16 cols
    {
        int rr = tid >> 4, c0 = (tid & 15) * 16;
        const float4* s = (const float4*)&hc1[(size_t)(b0 + rr) * 256 + c0];
        float4 a = s[0], b = s[1], c = s[2], d = s[3];
        *(half8*)&h_lds[0][rr * HS + c0]     = cvt8pair(a, b);
        *(half8*)&h_lds[0][rr * HS + c0 + 8] = cvt8pair(c, d);
    }
    // stage x(0) -> xf[0]: 512 threads x 1 float4
    {
        int rr = tid >> 4, c0 = (tid & 15) * 4;
        float4 v = *(const float4*)&x[(size_t)(b0 + rr) * 64 + c0];
        half4 h; h[0] = (_Float16)v.x; h[1] = (_Float16)v.y; h[2] = (_Float16)v.z; h[3] = (_Float16)v.w;
        *(half4*)&xf[0][rr * XS + c0] = h;
    }

    __syncthreads();

    // pipelined regions: r computes h_{r+1}; mid for step r-1; fc/out for r-2
    for (int r = 0; r < T_STEPS + 2; ++r) {
        const int cur = r & 1, nxt = cur ^ 1;

        if (r < T_STEPS) {
            // issue next-x global load early (latency hidden behind GEMM)
            float4 xv;
            const int xrow = tid >> 4, xc0 = (tid & 15) * 4;
            if (r <= T_STEPS - 2)
                xv = *(const float4*)&x[((size_t)(r + 1) * BATCH + b0 + xrow) * 64 + xc0];

            // pre = [x|h] @ [Wi;Wh]^T, processed per 16-row group (acc stays small)
            #pragma unroll
            for (int mt = 0; mt < 2; ++mt) {
                floatx4 acc0 = {0.f, 0.f, 0.f, 0.f};
                floatx4 acc1 = {0.f, 0.f, 0.f, 0.f};
                const int arow = mt * 16 + l16;
                #pragma unroll
                for (int ks = 0; ks < 8; ++ks) {
                    half8 af = *(const half8*)&h_lds[cur][arow * HS + ks * 32 + quad * 8];
                    acc0 = MFMA(af, wcat[2 + ks][0], acc0);
                    acc1 = MFMA(af, wcat[2 + ks][1], acc1);
                }
                #pragma unroll
                for (int ks = 0; ks < 2; ++ks) {
                    half8 af = *(const half8*)&xf[cur][arow * XS + ks * 32 + quad * 8];
                    acc0 = MFMA(af, wcat[ks][0], acc0);
                    acc1 = MFMA(af, wcat[ks][1], acc1);
                }
                // h_{r+1} = tanh(pre+bias) -> opposite parity buffer
                #pragma unroll
                for (int rr2 = 0; rr2 < 4; ++rr2) {
                    int row = mt * 16 + quad * 4 + rr2;
                    h_lds[nxt][row * HS + w * 32 + l16]      = (_Float16)fast_tanh(acc0[rr2] + bpre[0]);
                    h_lds[nxt][row * HS + w * 32 + 16 + l16] = (_Float16)fast_tanh(acc1[rr2] + bpre[1]);
                }
            }
            // finish x staging for r+1 (write to opposite parity)
            if (r <= T_STEPS - 2) {
                half4 h; h[0] = (_Float16)xv.x; h[1] = (_Float16)xv.y; h[2] = (_Float16)xv.z; h[3] = (_Float16)xv.w;
                *(half4*)&xf[nxt][xrow * XS + xc0] = h;
            }
        }

        if (r >= 1 && r <= T_STEPS) {
            // mid(r-1) = tanh(h_r @ Wo^T + bo); h_r lives in h_lds[cur]
            floatx4 acc2 = {0.f, 0.f, 0.f, 0.f};
            #pragma unroll
            for (int hv = 0; hv < 2; ++hv) {
                half8 wo4[4];
                #pragma unroll
                for (int i = 0; i < 4; ++i)
                    wo4[i] = *(const half8*)(wf16 + WS_WO + (size_t)midc * 256 + (hv * 4 + i) * 32 + quad * 8);
                #pragma unroll
                for (int i = 0; i < 4; ++i) {
                    half8 af = *(const half8*)&h_lds[cur][(midmt * 16 + l16) * HS + (hv * 4 + i) * 32 + quad * 8];
                    acc2 = MFMA(af, wo4[i], acc2);
                }
            }
            #pragma unroll
            for (int rr2 = 0; rr2 < 4; ++rr2) {
                int row = midmt * 16 + quad * 4 + rr2;
                midb[cur][row * MS + midc] = (_Float16)fast_tanh(acc2[rr2] + bo_r);
            }
        }

        if (tid < 128 && r >= 2) {
            // fc(r-2): reads midb[(r-1)&1] == midb[nxt]
            int row = tid >> 2, oc = tid & 3;
            float s = bfc_r;
            #pragma unroll
            for (int k8 = 0; k8 < 64; k8 += 8) {
                half8 mv = *(const half8*)&midb[nxt][row * MS + k8];
                half8 wv = *(const half8*)&wfc_lds[oc * 64 + k8];
                #pragma unroll
                for (int j = 0; j < 8; ++j)
                    s += (float)mv[j] * (float)wv[j];
            }
            out[((size_t)(r - 2) * BATCH + b0 + row) * 4 + oc] = s;
        }

        __syncthreads();
    }

    // h_final (fp32): h_16 lives in h_lds[16&1 == 0]
    {
        int rr = tid >> 4, c0 = (tid & 15) * 16;
        half8 p0 = *(const half8*)&h_lds[0][rr * HS + c0];
        half8 p1 = *(const half8*)&h_lds[0][rr * HS + c0 + 8];
        float4* dst = (float4*)&out[(size_t)T_STEPS * BATCH * 4 + (size_t)(b0 + rr) * 256 + c0];
        float4 v;
        v.x = (float)p0[0]; v.y = (float)p0[1]; v.z = (float)p0[2]; v.w = (float)p0[3]; dst[0] = v;
        v.x = (float)p0[4]; v.y = (float)p0[5]; v.z = (float)p0[6]; v.w = (float)p0[7]; dst[1] = v;
        v.x = (float)p1[0]; v.y = (float)p1[1]; v.z = (float)p1[2]; v.w = (float)p1[3]; dst[2] = v;
        v.x = (float)p1[4]; v.y = (float)p1[5]; v.z = (float)p1[6]; v.w = (float)p1[7]; dst[3] = v;
    }
}

extern "C" void kernel_launch(void* const* d_in, const int* in_sizes, int n_in,
                              void* d_out, int out_size, void* d_ws, size_t ws_size,
                              hipStream_t stream) {
    const float* x   = (const float*)d_in[0];
    const float* hc1 = (const float*)d_in[1];
    const float* Wi  = (const float*)d_in[2];
    const float* bi  = (const float*)d_in[3];
    const float* Wh  = (const float*)d_in[4];
    const float* bh  = (const float*)d_in[5];
    const float* Wo  = (const float*)d_in[6];
    const float* bo  = (const float*)d_in[7];
    const float* Wf  = (const float*)d_in[8];
    const float* bf  = (const float*)d_in[9];
    _Float16* ws = (_Float16*)d_ws;

    prep_kernel<<<(WS_TOT + 255) / 256, 256, 0, stream>>>(Wi, Wh, Wo, Wf, ws);
    rnn_kernel<<<BATCH / BLK_ROWS, 512, 0, stream>>>(
        x, hc1, ws, bi, bh, bo, bf, (float*)d_out);
}